// Round 3
// baseline (354.553 us; speedup 1.0000x reference)
//
#include <hip/hip_runtime.h>

#define B_ 4
#define H_ 16
#define SQ 1024
#define SK 1024
#define DHD 64
#define E_ 1024

typedef _Float16 half_t;
typedef __attribute__((ext_vector_type(8))) _Float16 half8;
typedef __attribute__((ext_vector_type(4))) _Float16 half4;
typedef __attribute__((ext_vector_type(4))) float f32x4;

static __device__ __forceinline__ f32x4 mfma16h(half8 a, half8 b, f32x4 c) {
  return __builtin_amdgcn_mfma_f32_16x16x32_f16(a, b, c, 0, 0, 0);
}

// ---- fp32 -> fp16 elementwise (8 elems/thread), optional negate ----
template <int NEG>
__global__ __launch_bounds__(256) void cvt_kernel(const float* __restrict__ src,
                                                  half_t* __restrict__ dst, int n8) {
  int i = blockIdx.x * 256 + threadIdx.x;
  if (i >= n8) return;
  f32x4 v0 = *(const f32x4*)(src + (size_t)i * 8);
  f32x4 v1 = *(const f32x4*)(src + (size_t)i * 8 + 4);
  half8 h;
#pragma unroll
  for (int j = 0; j < 4; ++j) {
    h[j] = (half_t)(NEG ? -v0[j] : v0[j]);
    h[4 + j] = (half_t)(NEG ? -v1[j] : v1[j]);
  }
  *(half8*)(dst + (size_t)i * 8) = h;
}

// ---- V transpose: [BH,Sk,64] f32 -> fp16 [BH,64,Sk] ----
__global__ __launch_bounds__(256) void vtrans_kernel(const float* __restrict__ V,
                                                     half_t* __restrict__ vt) {
  __shared__ float tile[64][65];
  int bh = blockIdx.x >> 4;
  int kt = blockIdx.x & 15;
  int tid = threadIdx.x;
  const float* src = V + ((size_t)bh * SK + (size_t)kt * 64) * DHD;
#pragma unroll
  for (int i = 0; i < 16; ++i) {
    int idx = i * 256 + tid;
    tile[idx >> 6][idx & 63] = src[idx];
  }
  __syncthreads();
#pragma unroll
  for (int i = 0; i < 16; ++i) {
    int idx = i * 256 + tid;
    int d = idx >> 6, kk = idx & 63;
    vt[((size_t)bh * DHD + d) * SK + kt * 64 + kk] = (half_t)tile[kk][d];
  }
}

// ---- q projection: fp16 GEMM, q = (emb @ Wq^T + bq) * 0.125, out [BH,Sq,64] fp16 ----
__global__ __launch_bounds__(256) void proj_kernel(const half_t* __restrict__ emb,
                                                   const half_t* __restrict__ wq,
                                                   const float* __restrict__ bq,
                                                   half_t* __restrict__ qh) {
  int tid = threadIdx.x, wid = tid >> 6, lane = tid & 63;
  int lr = lane & 15, lg = lane >> 4;
  int m0 = blockIdx.y * 64 + (wid >> 1) * 32;
  int n0 = blockIdx.x * 64 + (wid & 1) * 32;
  f32x4 acc[2][2];
#pragma unroll
  for (int i = 0; i < 2; ++i)
#pragma unroll
    for (int j = 0; j < 2; ++j) acc[i][j] = (f32x4){0.f, 0.f, 0.f, 0.f};

  for (int kk = 0; kk < E_; kk += 32) {
    half8 a[2], b[2];
#pragma unroll
    for (int g = 0; g < 2; ++g) {
      a[g] = *(const half8*)(emb + (size_t)(m0 + g * 16 + lr) * E_ + kk + lg * 8);
      b[g] = *(const half8*)(wq + (size_t)(n0 + g * 16 + lr) * E_ + kk + lg * 8);
    }
#pragma unroll
    for (int i = 0; i < 2; ++i)
#pragma unroll
      for (int j = 0; j < 2; ++j) acc[i][j] = mfma16h(a[i], b[j], acc[i][j]);
  }
#pragma unroll
  for (int i = 0; i < 2; ++i)
#pragma unroll
    for (int j = 0; j < 2; ++j)
#pragma unroll
      for (int r = 0; r < 4; ++r) {
        int m = m0 + i * 16 + lg * 4 + r;  // row=(lane>>4)*4+r
        int n = n0 + j * 16 + lr;          // col=lane&15
        float v = (acc[i][j][r] + bq[n]) * 0.125f;
        int b = m >> 10, sq = m & 1023, h = n >> 6, dd = n & 63;
        qh[((size_t)(b * H_ + h) * SQ + sq) * DHD + dd] = (half_t)v;
      }
}

// ---- fused attention, swapped-operand form ----
// T = M - K.q  (khn holds -K fp16, M loaded as MFMA C-input)
// C-layout: col = q = lane&15 (lane-local q-row), row = k = (lane>>4)*4+r
__global__ __launch_bounds__(256, 4) void attn_kernel(const half_t* __restrict__ qh,
                                                      const half_t* __restrict__ khn,
                                                      const half_t* __restrict__ vt,
                                                      const float* __restrict__ M,
                                                      const float* __restrict__ dpm,
                                                      float* __restrict__ out,
                                                      int* __restrict__ colmax) {
  __shared__ char panel[16 * 2048];  // P fp16 [16 q][1024 k], XOR-swizzled rows
  __shared__ float wred[4][16];
  __shared__ float gred[16];
  __shared__ float rowscale[16];

  // XCD-locality: all blocks of a bh land on one XCD (bid&7 = xcd round-robin)
  int bid = blockIdx.x;
  int x = bid & 7, j = bid >> 3;  // 4096 blocks = 8 x 512
  int bh = x * 8 + (j >> 6);      // 8 bh per XCD
  int q0 = (j & 63) << 4;         // 64 q-tiles of 16 rows
  int b = bh >> 4, h = bh & 15;

  int tid = threadIdx.x, wid = tid >> 6, lane = tid & 63;
  int lr = lane & 15, lg = lane >> 4;
  int kc0 = wid * 256;  // this wave's 256 k-rows

  // phase 1: T = M - K.q, all in registers (64 f32/lane, one q-row per lane)
  const float* mrow = M + ((size_t)bh * SQ + q0 + lr) * SK + kc0 + lg * 4;
  f32x4 T[16];
#pragma unroll
  for (int kt = 0; kt < 16; ++kt) T[kt] = *(const f32x4*)(mrow + kt * 16);

  const half_t* qrow = qh + ((size_t)bh * SQ + q0 + lr) * DHD;
  half8 qf0 = *(const half8*)(qrow + lg * 8);
  half8 qf1 = *(const half8*)(qrow + 32 + lg * 8);

#pragma unroll
  for (int kt = 0; kt < 16; ++kt) {
    const half_t* krow = khn + ((size_t)bh * SK + kc0 + kt * 16 + lr) * DHD;
    half8 k0 = *(const half8*)(krow + lg * 8);
    half8 k1 = *(const half8*)(krow + 32 + lg * 8);
    T[kt] = mfma16h(k0, qf0, T[kt]);
    T[kt] = mfma16h(k1, qf1, T[kt]);
  }

  // row min of T (== row max of S): per-lane + 2 shuffles + cross-wave LDS
  float mn = T[0][0];
#pragma unroll
  for (int kt = 0; kt < 16; ++kt)
#pragma unroll
    for (int r = 0; r < 4; ++r) mn = fminf(mn, T[kt][r]);
  mn = fminf(mn, __shfl_xor(mn, 16));
  mn = fminf(mn, __shfl_xor(mn, 32));
  if (lg == 0) wred[wid][lr] = mn;
  __syncthreads();
  if (tid < 16)
    gred[tid] = fminf(fminf(wred[0][tid], wred[1][tid]), fminf(wred[2][tid], wred[3][tid]));
  __syncthreads();
  float g = gred[lr];

  // p = exp(g - T) in (0,1]; write swizzled fp16 panel; row sums
  float ssum = 0.f;
#pragma unroll
  for (int kt = 0; kt < 16; ++kt) {
    half4 ph;
#pragma unroll
    for (int r = 0; r < 4; ++r) {
      float p = __expf(g - T[kt][r]);
      ssum += p;
      ph[r] = (half_t)p;
    }
    int k = kc0 + kt * 16 + lg * 4;
    *(half4*)(panel + ((lr * 2048 + k * 2) ^ ((lr & 7) << 4))) = ph;
  }
  ssum += __shfl_xor(ssum, 16);
  ssum += __shfl_xor(ssum, 32);
  if (lg == 0) wred[wid][lr] = ssum;
  __syncthreads();
  if (tid < 16)
    rowscale[tid] =
        dpm[b * SQ + q0 + tid] / (wred[0][tid] + wred[1][tid] + wred[2][tid] + wred[3][tid]);
  __syncthreads();

  // column max over the 16 q-rows -> device atomicMax (values >= 0)
  {
    int c0 = tid * 4;  // 256 threads x 4 consecutive cols
    f32x4 cm = (f32x4){0.f, 0.f, 0.f, 0.f};
#pragma unroll
    for (int r = 0; r < 16; ++r) {
      half4 ph = *(const half4*)(panel + ((r * 2048 + c0 * 2) ^ ((r & 7) << 4)));
      float rs = rowscale[r];
#pragma unroll
      for (int i = 0; i < 4; ++i) cm[i] = fmaxf(cm[i], (float)ph[i] * rs);
    }
#pragma unroll
    for (int i = 0; i < 4; ++i)
      atomicMax(colmax + (size_t)bh * SK + c0 + i, __float_as_int(cm[i]));
  }

  // PV: 4 waves = 4 d-tiles of 16; ctx^T[d][q] = V^T[d][k] . P^T[k][q]
  int d0 = wid * 16;
  const half_t* vrow = vt + ((size_t)bh * DHD + d0 + lr) * SK;
  f32x4 acc = (f32x4){0.f, 0.f, 0.f, 0.f};
#pragma unroll 8
  for (int ks = 0; ks < SK; ks += 32) {
    half8 av = *(const half8*)(vrow + ks + lg * 8);
    half8 bp = *(const half8*)(panel + ((lr * 2048 + (ks + lg * 8) * 2) ^ ((lr & 7) << 4)));
    acc = mfma16h(av, bp, acc);
  }
  float rs = rowscale[lr];
  f32x4 res;
#pragma unroll
  for (int r = 0; r < 4; ++r) res[r] = acc[r] * rs;
  *(f32x4*)(out + ((size_t)b * SQ + q0 + lr) * E_ + h * DHD + d0 + lg * 4) = res;
}

// ---- target_score = sum over heads of colmax ----
__global__ __launch_bounds__(256) void tscore_kernel(const int* __restrict__ colmax,
                                                     float* __restrict__ out) {
  int g = blockIdx.x * 256 + threadIdx.x;  // B*Sk = 4096
  int b = g >> 10, k = g & 1023;
  float s = 0.f;
#pragma unroll
  for (int hh = 0; hh < H_; ++hh) s += __int_as_float(colmax[((b * H_ + hh) << 10) + k]);
  out[(size_t)B_ * SQ * E_ + g] = s;
}

extern "C" void kernel_launch(void* const* d_in, const int* in_sizes, int n_in,
                              void* d_out, int out_size, void* d_ws, size_t ws_size,
                              hipStream_t stream) {
  const float* dp_emb = (const float*)d_in[0];
  const float* dp_mask = (const float*)d_in[1];
  const float* K = (const float*)d_in[2];
  const float* V = (const float*)d_in[3];
  const float* M = (const float*)d_in[4];
  const float* Wq = (const float*)d_in[5];
  const float* bq = (const float*)d_in[6];
  float* out = (float*)d_out;

  char* ws = (char*)d_ws;
  half_t* q_h = (half_t*)(ws);                    // 8 MB  [BH,Sq,64]
  half_t* k_hn = (half_t*)(ws + (8ull << 20));    // 8 MB  [BH,Sk,64] (negated)
  half_t* vt_h = (half_t*)(ws + (16ull << 20));   // 8 MB  [BH,64,Sk]
  half_t* emb_h = (half_t*)(ws + (24ull << 20));  // 8 MB  [B*Sq,E]
  half_t* wq_h = (half_t*)(ws + (32ull << 20));   // 2 MB  [E,E]
  int* colmax = (int*)(ws + (35ull << 20));       // 256 KB

  hipMemsetAsync(colmax, 0, (size_t)B_ * H_ * SK * sizeof(int), stream);
  cvt_kernel<0><<<(B_ * SQ * E_ / 8 + 255) / 256, 256, 0, stream>>>(dp_emb, emb_h,
                                                                    B_ * SQ * E_ / 8);
  cvt_kernel<0><<<(E_ * E_ / 8 + 255) / 256, 256, 0, stream>>>(Wq, wq_h, E_ * E_ / 8);
  cvt_kernel<1><<<(B_ * H_ * SK * DHD / 8 + 255) / 256, 256, 0, stream>>>(
      K, k_hn, B_ * H_ * SK * DHD / 8);
  vtrans_kernel<<<B_ * H_ * 16, 256, 0, stream>>>(V, vt_h);
  proj_kernel<<<dim3(E_ / 64, (B_ * SQ) / 64), 256, 0, stream>>>(emb_h, wq_h, bq, q_h);
  attn_kernel<<<B_ * H_ * (SQ / 16), 256, 0, stream>>>(q_h, k_hn, vt_h, M, dp_mask, out,
                                                       colmax);
  tscore_kernel<<<(B_ * SK) / 256, 256, 0, stream>>>(colmax, out);
}